// Round 1
// baseline (1046.050 us; speedup 1.0000x reference)
//
#include <hip/hip_runtime.h>
#include <math.h>

// Problem dims (fixed by setup_inputs)
#define B_SZ 256
#define D_SZ 512
#define K_SZ 128000
#define N_SZ 100000

// Workspace layout (bytes). Total ~133.6 MB required.
#define OFF_T     0UL          // t_f32      [256*512] f32
#define OFF_Q     524288UL     // q_f32      [256*512] f32
#define OFF_TH    1048576UL    // t_f16      [256*512] f16
#define OFF_CTH   1310720UL    // ct_f16     [256*512] f16
#define OFF_NPQ   1572864UL    // new_pq     [100000] i32
#define OFF_TPROW 1973248UL    // tp_row     [128000] i32
#define OFF_UN    2485248UL    // un_idx     [256*5] i32
#define OFF_IDXP  2490880UL    // idxp       [256*10] i32
#define OFF_SC    2501632UL    // scores     [256*128000] f32 (reused by both GEMMs)

typedef __attribute__((ext_vector_type(4))) float    f32x4;
typedef __attribute__((ext_vector_type(8))) _Float16 f16x8;

// ---------------- block-wide sum over 256 threads ----------------
__device__ __forceinline__ float block_sum(float v, float* red) {
  #pragma unroll
  for (int o = 32; o > 0; o >>= 1) v += __shfl_down(v, o, 64);
  const int w = threadIdx.x >> 6;
  const int l = threadIdx.x & 63;
  __syncthreads();                 // protect red[] reuse across calls
  if (l == 0) red[w] = v;
  __syncthreads();
  return red[0] + red[1] + red[2] + red[3];
}

// ---------------- prep: normalize q,t; gather ct_prime ----------------
__global__ __launch_bounds__(256) void prep_rows_kernel(
    const float* __restrict__ query, const float* __restrict__ ctar,
    const float* __restrict__ pool, const int* __restrict__ pool_qindex,
    const int* __restrict__ indices,
    float* __restrict__ t_f32, float* __restrict__ q_f32,
    _Float16* __restrict__ t_f16, _Float16* __restrict__ ct_f16)
{
  __shared__ float red[4];
  const int b = blockIdx.x, tid = threadIdx.x;
  const long base = (long)b * D_SZ;
  float x0 = query[base + tid], x1 = query[base + 256 + tid];
  float y0 = ctar[base + tid],  y1 = ctar[base + 256 + tid];
  float sq = block_sum(x0 * x0 + x1 * x1, red);
  float st = block_sum(y0 * y0 + y1 * y1, red);
  float rq = 1.f / sqrtf(sq);
  float rt = 1.f / sqrtf(st);
  q_f32[base + tid] = x0 * rq; q_f32[base + 256 + tid] = x1 * rq;
  float t0 = y0 * rt, t1 = y1 * rt;
  t_f32[base + tid] = t0; t_f32[base + 256 + tid] = t1;
  t_f16[base + tid] = (_Float16)t0; t_f16[base + 256 + tid] = (_Float16)t1;
  // ct_prime[b] = pool[1 - pq[indices[b]], indices[b]] (post-flip slot == un-written slot)
  int i = indices[b];
  int slot = 1 - pool_qindex[i];
  const float* pr = pool + ((long)slot * N_SZ + i) * D_SZ;
  ct_f16[base + tid] = (_Float16)pr[tid];
  ct_f16[base + 256 + tid] = (_Float16)pr[tid + 256];
}

__global__ void prep_newpq_kernel(const int* __restrict__ pq, int* __restrict__ new_pq) {
  int i = blockIdx.x * 256 + threadIdx.x;
  if (i < N_SZ) new_pq[i] = pq[i];
}

__global__ void prep_flip_kernel(const int* __restrict__ pq, const int* __restrict__ indices,
                                 int* __restrict__ new_pq) {
  int i = indices[threadIdx.x];           // 1 block x 256; dup indices write same value
  new_pq[i] = 1 - pq[i];
}

__global__ void prep_tprow_kernel(const int* __restrict__ new_pq,
                                  const int* __restrict__ index_queue,
                                  const int* __restrict__ indices,
                                  int* __restrict__ tp_row) {
  int k = blockIdx.x * 256 + threadIdx.x; // 500 blocks -> exactly 128000
  int i = (k < B_SZ) ? indices[k] : index_queue[k];
  tp_row[k] = new_pq[i] * N_SZ + i;
}

// ---------------- selection GEMM: scores[b][k] = rowA(b) . rowB(k) ----------------
// MODE 0: A = t_f16, B(k) = (k<256 ? t : queue[k])    (new queue)
// MODE 1: A = ct_f16, B(k) = pool[tp_row[k]]          (targets_prime)
// Block: 256 thr (4 waves). M=256 (A-frags wave-private, straight from L2).
// N-tile 64/block, K chunked by 64 through LDS (fp32 -> f16 convert in staging).
template<int MODE>
__global__ __launch_bounds__(256) void gemm_kernel(
    const float* __restrict__ queue, const float* __restrict__ pool,
    const float* __restrict__ t_f32, const _Float16* __restrict__ A_f16,
    const int* __restrict__ tp_row, float* __restrict__ scores)
{
  __shared__ __align__(16) _Float16 B_lds[64 * 72];   // stride 72 (+8 pad) kills bank conflicts
  const int tid  = threadIdx.x;
  const int lane = tid & 63;
  const int w    = tid >> 6;
  const int quad = lane >> 4;
  const int l15  = lane & 15;
  const long col0 = (long)blockIdx.x * 64;

  // B staging assignment: thread -> (row 0..63, 16-float chunk 0..3)
  const int brow = tid >> 2;
  const int bch  = tid & 3;
  const long gcol = col0 + brow;
  const float* bsrc;
  if (MODE == 0) {
    bsrc = (gcol < B_SZ) ? (t_f32 + gcol * D_SZ) : (queue + gcol * D_SZ);
  } else {
    bsrc = pool + (long)tp_row[gcol] * D_SZ;
  }
  bsrc += bch * 16;

  f32x4 acc[4][4];
  #pragma unroll
  for (int mt = 0; mt < 4; ++mt)
    #pragma unroll
    for (int nt = 0; nt < 4; ++nt) acc[mt][nt] = (f32x4){0.f, 0.f, 0.f, 0.f};

  // A-frag base: A[m = w*64 + mt*16 + l15][k = kc + ks*32 + quad*8 .. +7]
  const _Float16* arow = A_f16 + (long)(w * 64 + l15) * D_SZ + quad * 8;

  #pragma unroll 1
  for (int kc = 0; kc < D_SZ; kc += 64) {
    // stage B: 16 fp32 -> 16 f16 per thread
    float4 f0 = *(const float4*)(bsrc + kc + 0);
    float4 f1 = *(const float4*)(bsrc + kc + 4);
    float4 f2 = *(const float4*)(bsrc + kc + 8);
    float4 f3 = *(const float4*)(bsrc + kc + 12);
    f16x8 w0, w1;
    w0[0] = (_Float16)f0.x; w0[1] = (_Float16)f0.y; w0[2] = (_Float16)f0.z; w0[3] = (_Float16)f0.w;
    w0[4] = (_Float16)f1.x; w0[5] = (_Float16)f1.y; w0[6] = (_Float16)f1.z; w0[7] = (_Float16)f1.w;
    w1[0] = (_Float16)f2.x; w1[1] = (_Float16)f2.y; w1[2] = (_Float16)f2.z; w1[3] = (_Float16)f2.w;
    w1[4] = (_Float16)f3.x; w1[5] = (_Float16)f3.y; w1[6] = (_Float16)f3.z; w1[7] = (_Float16)f3.w;
    *(f16x8*)(&B_lds[brow * 72 + bch * 16])     = w0;
    *(f16x8*)(&B_lds[brow * 72 + bch * 16 + 8]) = w1;
    __syncthreads();
    #pragma unroll
    for (int ks = 0; ks < 2; ++ks) {
      f16x8 af[4], bfr[4];
      #pragma unroll
      for (int mt = 0; mt < 4; ++mt)
        af[mt] = *(const f16x8*)(arow + (long)mt * 16 * D_SZ + kc + ks * 32);
      #pragma unroll
      for (int nt = 0; nt < 4; ++nt)
        bfr[nt] = *(const f16x8*)(&B_lds[(nt * 16 + l15) * 72 + ks * 32 + quad * 8]);
      #pragma unroll
      for (int mt = 0; mt < 4; ++mt)
        #pragma unroll
        for (int nt = 0; nt < 4; ++nt)
          acc[mt][nt] = __builtin_amdgcn_mfma_f32_16x16x32_f16(af[mt], bfr[nt], acc[mt][nt], 0, 0, 0);
    }
    __syncthreads();
  }

  // epilogue: C row = (lane>>4)*4 + reg, col = lane&15  [measured layout, m89/m91]
  #pragma unroll
  for (int mt = 0; mt < 4; ++mt) {
    int row0 = w * 64 + mt * 16 + quad * 4;
    #pragma unroll
    for (int i = 0; i < 4; ++i) {
      long rbase = (long)(row0 + i) * K_SZ + col0;
      #pragma unroll
      for (int nt = 0; nt < 4; ++nt)
        scores[rbase + nt * 16 + l15] = acc[mt][nt][i];
    }
  }
}

// ---------------- per-row top-K (largest score, tie -> smaller index) ----------------
template<int KS>
__global__ __launch_bounds__(256) void topk_kernel(
    const float* __restrict__ scores, int* __restrict__ out_idx)
{
  __shared__ float sv[256 * KS];
  __shared__ int   si[256 * KS];
  const int r = blockIdx.x;
  const int tid = threadIdx.x;
  float bv[KS]; int bi[KS];
  #pragma unroll
  for (int j = 0; j < KS; ++j) { bv[j] = -3.4e38f; bi[j] = 0x7fffffff; }
  const float4* srow = (const float4*)(scores + (long)r * K_SZ);
  for (int it = 0; it < K_SZ / 1024; ++it) {      // 125 iters, float4 per thread
    float4 v4 = srow[it * 256 + tid];
    int kb = (it * 256 + tid) * 4;
    float vv[4] = {v4.x, v4.y, v4.z, v4.w};
    #pragma unroll
    for (int j = 0; j < 4; ++j) {
      float v = vv[j];
      if (v > bv[KS - 1]) {                        // k ascending per-thread: strict > keeps smaller idx on ties
        bv[KS - 1] = v; bi[KS - 1] = kb + j;
        #pragma unroll
        for (int m = KS - 1; m > 0; --m) {
          if (bv[m] > bv[m - 1]) {
            float tv = bv[m]; bv[m] = bv[m - 1]; bv[m - 1] = tv;
            int   ti = bi[m]; bi[m] = bi[m - 1]; bi[m - 1] = ti;
          }
        }
      }
    }
  }
  #pragma unroll
  for (int j = 0; j < KS; ++j) { sv[tid * KS + j] = bv[j]; si[tid * KS + j] = bi[j]; }
  for (int s = 128; s > 0; s >>= 1) {
    __syncthreads();
    if (tid < s) {
      int pa = tid * KS, pb = (tid + s) * KS;
      float mv[KS]; int mi[KS];
      int ia = 0, ib = 0;
      #pragma unroll
      for (int j = 0; j < KS; ++j) {
        float va = sv[pa + ia], vb = sv[pb + ib];
        int   xa = si[pa + ia], xb = si[pb + ib];
        bool ta = (va > vb) || (va == vb && xa < xb);
        mv[j] = ta ? va : vb; mi[j] = ta ? xa : xb;
        if (ta) ++ia; else ++ib;
      }
      #pragma unroll
      for (int j = 0; j < KS; ++j) { sv[pa + j] = mv[j]; si[pa + j] = mi[j]; }
    }
  }
  __syncthreads();
  if (tid < KS) out_idx[r * KS + tid] = si[tid];
}

// ---------------- finalize: exact fp32 distances at selected cols, loss+purity ----------------
__global__ __launch_bounds__(256) void finalize_kernel(
    const float* __restrict__ t_f32, const float* __restrict__ q_f32,
    const float* __restrict__ queue,
    const int* __restrict__ un_idx, const int* __restrict__ idxp,
    const int* __restrict__ labels_bank, const int* __restrict__ labels,
    float* __restrict__ out)
{
  __shared__ float red[4];
  __shared__ float dvals[10];
  __shared__ int   csel[5];
  const int b = blockIdx.x;
  const int tid = threadIdx.x;
  const float* trow = t_f32 + (long)b * D_SZ;
  const float* qrow = q_f32 + (long)b * D_SZ;

  // dist_t at the 10 constrained columns (new-queue rows: col<256 -> t)
  #pragma unroll 1
  for (int j = 0; j < 10; ++j) {
    int c = idxp[b * 10 + j];
    const float* cp = (c < B_SZ) ? (t_f32 + (long)c * D_SZ) : (queue + (long)c * D_SZ);
    float p = trow[tid] * cp[tid] + trow[tid + 256] * cp[tid + 256];
    float s = block_sum(p, red);
    if (tid == 0) dvals[j] = 2.f - 2.f * s;
  }
  __syncthreads();
  // pick 5 of 10 by (dist_t asc, idx asc) — equals ref's top_k after the -5 scatter
  if (tid == 0) {
    unsigned used = 0;
    for (int m = 0; m < 5; ++m) {
      int best = -1; float bd = 0.f; int bc = 0;
      for (int j = 0; j < 10; ++j) {
        if (used & (1u << j)) continue;
        float dj = dvals[j]; int cj = idxp[b * 10 + j];
        if (best < 0 || dj < bd || (dj == bd && cj < bc)) { best = j; bd = dj; bc = cj; }
      }
      used |= 1u << best;
      csel[m] = idxp[b * 10 + best];
    }
  }
  __syncthreads();

  float con_s = 0.f, un_s = 0.f;
  #pragma unroll 1
  for (int m = 0; m < 5; ++m) {
    int c = csel[m];
    const float* cp = (c < B_SZ) ? (t_f32 + (long)c * D_SZ) : (queue + (long)c * D_SZ);
    float p = qrow[tid] * cp[tid] + qrow[tid + 256] * cp[tid + 256];
    con_s += block_sum(p, red);
  }
  int match = 0;
  #pragma unroll 1
  for (int m = 0; m < 5; ++m) {
    int c = un_idx[b * 5 + m];
    const float* cp = (c < B_SZ) ? (t_f32 + (long)c * D_SZ) : (queue + (long)c * D_SZ);
    float p = qrow[tid] * cp[tid] + qrow[tid + 256] * cp[tid + 256];
    un_s += block_sum(p, red);
    if (tid == 0) {
      int lb = (c < B_SZ) ? labels[c] : labels_bank[c];   // labels_bank[:B] = labels
      match += (lb == labels[b]) ? 1 : 0;
    }
  }
  if (tid == 0) {
    float con_sum = 10.f - 2.f * con_s;   // sum of 5 x (2-2s)
    float un_sum  = 10.f - 2.f * un_s;
    float lossc = (con_sum * 0.2f + un_sum * 0.2f) * 0.5f * (1.f / 256.f);
    atomicAdd(out + 0, lossc);
    atomicAdd(out + 1, (float)match * 0.2f * (1.f / 256.f));
  }
}

// ---------------- launch ----------------
extern "C" void kernel_launch(void* const* d_in, const int* in_sizes, int n_in,
                              void* d_out, int out_size, void* d_ws, size_t ws_size,
                              hipStream_t stream) {
  const float* query       = (const float*)d_in[0];
  const float* ctar        = (const float*)d_in[1];
  const float* queue       = (const float*)d_in[2];
  const float* pool        = (const float*)d_in[3];
  const int*   labels_bank = (const int*)d_in[4];
  const int*   index_queue = (const int*)d_in[5];
  const int*   pool_qindex = (const int*)d_in[6];
  const int*   labels      = (const int*)d_in[7];
  const int*   indices     = (const int*)d_in[8];

  char* ws = (char*)d_ws;
  float*     t_f32  = (float*)(ws + OFF_T);
  float*     q_f32  = (float*)(ws + OFF_Q);
  _Float16*  t_f16  = (_Float16*)(ws + OFF_TH);
  _Float16*  ct_f16 = (_Float16*)(ws + OFF_CTH);
  int*       new_pq = (int*)(ws + OFF_NPQ);
  int*       tp_row = (int*)(ws + OFF_TPROW);
  int*       un_idx = (int*)(ws + OFF_UN);
  int*       idxp   = (int*)(ws + OFF_IDXP);
  float*     scores = (float*)(ws + OFF_SC);
  float*     out    = (float*)d_out;

  hipMemsetAsync(out, 0, 2 * sizeof(float), stream);

  prep_rows_kernel<<<B_SZ, 256, 0, stream>>>(query, ctar, pool, pool_qindex, indices,
                                             t_f32, q_f32, t_f16, ct_f16);
  prep_newpq_kernel<<<(N_SZ + 255) / 256, 256, 0, stream>>>(pool_qindex, new_pq);
  prep_flip_kernel<<<1, 256, 0, stream>>>(pool_qindex, indices, new_pq);
  prep_tprow_kernel<<<K_SZ / 256, 256, 0, stream>>>(new_pq, index_queue, indices, tp_row);

  gemm_kernel<0><<<K_SZ / 64, 256, 0, stream>>>(queue, pool, t_f32, t_f16, tp_row, scores);
  topk_kernel<5><<<B_SZ, 256, 0, stream>>>(scores, un_idx);

  gemm_kernel<1><<<K_SZ / 64, 256, 0, stream>>>(queue, pool, t_f32, ct_f16, tp_row, scores);
  topk_kernel<10><<<B_SZ, 256, 0, stream>>>(scores, idxp);

  finalize_kernel<<<B_SZ, 256, 0, stream>>>(t_f32, q_f32, queue, un_idx, idxp,
                                            labels_bank, labels, out);
}